// Round 1
// baseline (289.037 us; speedup 1.0000x reference)
//
#include <hip/hip_runtime.h>
#include <hip/hip_bf16.h>

typedef __hip_bfloat16 bf16;
typedef unsigned short us;
typedef __attribute__((ext_vector_type(8))) short short8;
typedef __attribute__((ext_vector_type(4))) float floatx4;

__device__ __forceinline__ float b2f(bf16 v){ return __bfloat162float(v); }
__device__ __forceinline__ bf16  f2b(float v){ return __float2bfloat16(v); }
__device__ __forceinline__ float ldx(const void* p, size_t i, int isf){
    return isf ? ((const float*)p)[i] : b2f(((const bf16*)p)[i]);
}
__device__ __forceinline__ us bfbits(float v){
    bf16 h = f2b(v); return *(us*)&h;
}
__device__ __forceinline__ float us2f(us u){
    unsigned int w = ((unsigned int)u)<<16; float f; __builtin_memcpy(&f,&w,4); return f;
}

#define BB   16
#define CC   64
#define HH   144
#define WW   144
#define HS   48
#define SP   (HS*HS)            // 2304
#define NTOT (BB*CC*HH*WW)      // 21233664
#define NCH  36864              // B*SP
#define INV_NCH (1.f/36864.f)

// -------- 0. init: dtype sniff + zero stats --------------------------------
__global__ void k_init(const unsigned int* __restrict__ x, int* __restrict__ flag,
                       float* __restrict__ stats){
    for(int i=threadIdx.x; i<1280; i+=256) stats[i] = 0.f;
    __shared__ int hit;
    if(threadIdx.x==0) hit = 0;
    __syncthreads();
    int local = 0;
    for(int t=threadIdx.x; t<4096; t+=256){
        unsigned int w = x[t];
        if(((w>>7)&0xFFu)==0xFFu || ((w>>23)&0xFFu)==0xFFu) local = 1;
    }
    if(local) atomicOr(&hit, 1);
    __syncthreads();
    if(threadIdx.x==0) *flag = hit;
}

// -------- 1. maxpool 3x3 s1 p1, writes FOCUS layout ------------------------
// pf[b][gi][gj][c][y][xx] = maxpool(x)[b,c,3y+gi,3xx+gj]
__global__ __launch_bounds__(256) void k_pool3(const void* __restrict__ x,
                                               us* __restrict__ pf,
                                               const int* __restrict__ flag){
    __shared__ float l [18*148];
    __shared__ float hm[18*148];
    int isf = *flag;
    int bid = blockIdx.x;
    int strip = bid % 9;
    int bc = bid / 9;
    int b = bc>>6, c = bc&63;
    int r0 = strip*16;
    size_t base = (size_t)bc*HH*WW;
    int tid = threadIdx.x;
    // load rows r0-1 .. r0+16 (18 rows x 144), 8-wide vectors
    for(int t=tid; t<18*18; t+=256){
        int row = t/18, ch = t%18;
        int rr = r0-1+row; int c0 = ch*8;
        float v[8];
        if(rr>=0 && rr<HH){
            if(isf){
                const float* xp = (const float*)x + base + (size_t)rr*WW + c0;
                float4 f0 = *(const float4*)xp;
                float4 f1 = *(const float4*)(xp+4);
                v[0]=f0.x;v[1]=f0.y;v[2]=f0.z;v[3]=f0.w;
                v[4]=f1.x;v[5]=f1.y;v[6]=f1.z;v[7]=f1.w;
            } else {
                const us* xp = (const us*)x + base + (size_t)rr*WW + c0;
                uint4 d = *(const uint4*)xp;
                const us* u = (const us*)&d;
                #pragma unroll
                for(int e=0;e<8;++e) v[e] = us2f(u[e]);
            }
        } else {
            #pragma unroll
            for(int e=0;e<8;++e) v[e] = -INFINITY;
        }
        #pragma unroll
        for(int e=0;e<8;++e) l[row*148 + c0 + e] = v[e];
    }
    __syncthreads();
    for(int t=tid; t<18*144; t+=256){
        int row = t/144, cc = t%144;
        float a = l[row*148+cc];
        float bb = (cc>0)   ? l[row*148+cc-1] : -INFINITY;
        float cv = (cc<143) ? l[row*148+cc+1] : -INFINITY;
        hm[row*148+cc] = fmaxf(a, fmaxf(bb,cv));
    }
    __syncthreads();
    // vmax + scatter to focus layout; 4 outputs (same gj) per iter
    for(int t=tid; t<576; t+=256){
        int row = t/36;
        int gj  = (t/12)%3;
        int xg  = t%12;
        int R = r0+row;
        int gi = R%3, y = R/3;
        union { us u[4]; uint2 v; } pk;
        #pragma unroll
        for(int e=0;e<4;++e){
            int xx = xg*4+e; int C = 3*xx+gj;
            float m = fmaxf(hm[row*148+C],
                      fmaxf(hm[(row+1)*148+C], hm[(row+2)*148+C]));
            pk.u[e] = bfbits(m);
        }
        size_t o = ((((size_t)(b*3+gi)*3+gj)*64 + c)*48 + y)*48 + xg*4;
        *(uint2*)&pf[o] = pk.v;
    }
}

// -------- 2. MFMA mixer + BN1 stats ----------------------------------------
// block = (b,g,chunk): C[64 o][288 sites] = W_g[64x64] x I[64x288]
// LDS swizzle: element (row, i) at row*64 + ((i/8 + row)%8)*8 + i%8
__global__ __launch_bounds__(256) void k_mix3(const us* __restrict__ pf,
        const void* __restrict__ wmix, us* __restrict__ mixed,
        float* __restrict__ sum1, float* __restrict__ ss1,
        const int* __restrict__ flag){
    __shared__ __align__(16) us sW[4096];
    __shared__ __align__(16) us sI[288*64];
    __shared__ float sS[64], sQ[64];
    int isf = *flag;
    int bid = blockIdx.x;
    int chunk = bid%8, g = (bid/8)%9, b = bid/72;
    int gi = g/3, gj = g%3;
    int tid = threadIdx.x, lane = tid&63, w = tid>>6;
    // stage W (swizzled): thread -> o=tid/4, i-range 16
    {
        int o  = tid>>2;
        int i0 = (tid&3)*16;
        #pragma unroll
        for(int e=0;e<16;++e){
            int i = i0+e;
            float v = ldx(wmix, (size_t)g*4096 + (size_t)o*64 + i, isf);
            sW[o*64 + ((((i>>3)+o)&7)<<3) + (i&7)] = bfbits(v);
        }
    }
    if(tid<64){ sS[tid]=0.f; sQ[tid]=0.f; }
    // stage I (swizzled): lane = channel i, wave covers 9 vec8 chunks
    {
        int i = lane;
        const us* src = pf + ((((size_t)(b*3+gi)*3+gj)*64 + i)*48 + (size_t)chunk*6)*48;
        for(int vv=w*9; vv<(w+1)*9; ++vv){
            uint4 d = *(const uint4*)(src + vv*8);
            const us* u = (const us*)&d;
            #pragma unroll
            for(int e=0;e<8;++e){
                int s = vv*8+e;
                sI[s*64 + ((((i>>3)+s)&7)<<3) + (i&7)] = u[e];
            }
        }
    }
    __syncthreads();
    int n = lane&15, quad = lane>>4;
    int m = w*16 + n;   // this wave's A rows (o)
    // A fragments for k0=0 (q2=quad) and k0=32 (q2=4+quad)
    short8 a0 = *(const short8*)&sW[m*64 + (((quad     + m)&7)<<3)];
    short8 a1 = *(const short8*)&sW[m*64 + ((((4+quad) + m)&7)<<3)];
    floatx4 acc[18];
    #pragma unroll
    for(int nt=0; nt<18; ++nt) acc[nt] = (floatx4){0.f,0.f,0.f,0.f};
    #pragma unroll
    for(int nt=0; nt<18; ++nt){
        int site = nt*16 + n;
        short8 b0 = *(const short8*)&sI[site*64 + (((quad     + site)&7)<<3)];
        short8 b1 = *(const short8*)&sI[site*64 + ((((4+quad) + site)&7)<<3)];
        acc[nt] = __builtin_amdgcn_mfma_f32_16x16x32_bf16(a0, b0, acc[nt], 0,0,0);
        acc[nt] = __builtin_amdgcn_mfma_f32_16x16x32_bf16(a1, b1, acc[nt], 0,0,0);
    }
    // store + per-lane stats.  C layout: col=lane&15 (site), row=quad*4+r (o)
    size_t obase = (size_t)(b*576 + g*64)*SP + (size_t)chunk*288;
    float s[4] = {0,0,0,0}, q[4] = {0,0,0,0};
    #pragma unroll
    for(int nt=0; nt<18; ++nt){
        #pragma unroll
        for(int r=0;r<4;++r){
            float v = acc[nt][r];
            int o = w*16 + quad*4 + r;
            mixed[obase + (size_t)o*SP + nt*16 + n] = bfbits(v);
            s[r] += v; q[r] += v*v;
        }
    }
    #pragma unroll
    for(int off=1; off<=8; off<<=1){
        #pragma unroll
        for(int r=0;r<4;++r){
            s[r] += __shfl_xor(s[r], off, 64);
            q[r] += __shfl_xor(q[r], off, 64);
        }
    }
    if(n==0){
        #pragma unroll
        for(int r=0;r<4;++r){
            atomicAdd(&sS[w*16+quad*4+r], s[r]);
            atomicAdd(&sQ[w*16+quad*4+r], q[r]);
        }
    }
    __syncthreads();
    if(tid<64){
        atomicAdd(&sum1[g*64+tid], sS[tid]);
        atomicAdd(&ss1 [g*64+tid], sQ[tid]);
    }
}

// -------- 3. fused 4-way depthwise conv + BN1 inline + BN2 stats -----------
// Register-blocked 4 outputs/thread.  conv3 (taps [h+u][w+v-u]) and conv4
// (taps [h+v-u][w+u]) read the SAME 6-wide window at row offset r, so their
// weights merge into one 13x3 table w34[r][v] (zero-padded at |r|=6).
__global__ __launch_bounds__(256) void k_conv3(const us* __restrict__ mixed,
    const float* __restrict__ sum1, const float* __restrict__ ss1,
    const void* __restrict__ gm, const void* __restrict__ bm,
    const void* __restrict__ wh1, const void* __restrict__ wv1,
    const void* __restrict__ wh2, const void* __restrict__ wv2,
    us* __restrict__ att, float* __restrict__ sum2, float* __restrict__ ss2,
    const int* __restrict__ flag){
    __shared__ float tile[60*60+4];
    __shared__ float w1[33], w2[33], w34[39];
    __shared__ float r1[256], r2[256];
    int isf = *flag;
    int bid = blockIdx.x;
    int b = bid/64, c = bid%64;
    int tid = threadIdx.x;
    for(int t=tid; t<3604; t+=256) tile[t] = 0.f;
    if(tid < 33){
        w1[tid] = ldx(wh1, c*33 + tid, isf);
    } else if(tid < 66){
        w2[tid-33] = ldx(wv1, c*33 + (tid-33), isf);
    } else if(tid < 105){
        int k = tid-66;            // 0..38 : 13 rows x 3
        int r = k/3 - 6;           // row offset -6..6
        int vo = k%3 - 1;          // original v  -1..1
        float a = 0.f;
        if(r >= -5 && r <= 5)      // conv3 (h-transform), u = r
            a += ldx(wh2, c*33 + (r+5)*3 + (vo+1), isf);
        int u = vo - r;            // conv4 (v-transform), row off = vo-u
        if(u >= -5 && u <= 5)
            a += ldx(wv2, c*33 + (vo+1)*11 + (u+5), isf);
        w34[k] = a;
    }
    __syncthreads();
    // BN1 params for this channel (computed from raw sums — finstats folded in)
    float mu   = sum1[c]*INV_NCH;
    float var  = ss1[c]*INV_NCH - mu*mu;
    float is   = rsqrtf(var + 1e-5f)*ldx(gm,c,isf);
    float be   = ldx(bm,c,isf);
    const us* src = mixed + (size_t)(b*576 + c)*SP;
    for(int t=tid; t<288; t+=256){
        int h = t/6, w0 = (t%6)*8;
        uint4 d = *(const uint4*)(src + t*8);
        const us* u = (const us*)&d;
        #pragma unroll
        for(int e=0;e<8;++e)
            tile[(h+6)*60 + (w0+6) + e] = (us2f(u[e]) - mu)*is + be;
    }
    __syncthreads();
    us* out = att + (size_t)(b*64 + c)*SP;
    float sl = 0.f, ql = 0.f;
    for(int t=tid; t<576; t+=256){
        int hh = t/12 + 6;
        int w0 = (t%12)*4 + 6;
        float a0=0.f, a1=0.f, a2=0.f, a3=0.f;
        // conv2 (3x11): rows hh-1..hh+1, window 14 wide
        #pragma unroll
        for(int r=-1; r<=1; ++r){
            const float* rp = &tile[(hh+r)*60 + w0];
            float Cw[14];
            #pragma unroll
            for(int j=0;j<14;++j) Cw[j] = rp[j-5];
            #pragma unroll
            for(int v=0;v<11;++v){
                float wv = w2[(r+1)*11 + v];
                a0 += wv*Cw[v];   a1 += wv*Cw[v+1];
                a2 += wv*Cw[v+2]; a3 += wv*Cw[v+3];
            }
        }
        // conv1 (11x3) + merged conv3/conv4 (13x3 diagonal)
        #pragma unroll
        for(int r=-6; r<=6; ++r){
            const float* rp = &tile[(hh+r)*60 + w0];
            float Aw[6];
            #pragma unroll
            for(int j=0;j<6;++j) Aw[j] = rp[j-1-r];   // shifted window, shared by conv3+conv4
            #pragma unroll
            for(int v=0;v<3;++v){
                float wv = w34[(r+6)*3 + v];
                a0 += wv*Aw[v];   a1 += wv*Aw[v+1];
                a2 += wv*Aw[v+2]; a3 += wv*Aw[v+3];
            }
            if(r >= -5 && r <= 5){
                float Bw[6];
                #pragma unroll
                for(int j=0;j<6;++j) Bw[j] = rp[j-1];
                #pragma unroll
                for(int v=0;v<3;++v){
                    float wv = w1[(r+5)*3 + v];
                    a0 += wv*Bw[v];   a1 += wv*Bw[v+1];
                    a2 += wv*Bw[v+2]; a3 += wv*Bw[v+3];
                }
            }
        }
        int o = (hh-6)*48 + (w0-6);
        union { us u[4]; uint2 v; } pk;
        pk.u[0]=bfbits(a0); pk.u[1]=bfbits(a1);
        pk.u[2]=bfbits(a2); pk.u[3]=bfbits(a3);
        *(uint2*)&out[o] = pk.v;
        sl += a0+a1+a2+a3;
        ql += a0*a0+a1*a1+a2*a2+a3*a3;
    }
    r1[tid]=sl; r2[tid]=ql; __syncthreads();
    for(int o=128;o>0;o>>=1){
        if(tid<o){ r1[tid]+=r1[tid+o]; r2[tid]+=r2[tid+o]; }
        __syncthreads();
    }
    if(tid==0){
        atomicAdd(&sum2[c], r1[0]);
        atomicAdd(&ss2 [c], r2[0]);
    }
}

// -------- 4. final: BN + pixel_shuffle + sigmoid gate (y-split) ------------
__global__ __launch_bounds__(256) void k_final3(const void* __restrict__ x,
    const us* __restrict__ mixed, const us* __restrict__ att,
    const void* __restrict__ gm, const void* __restrict__ bm,
    const void* __restrict__ gn, const void* __restrict__ bnb,
    const float* __restrict__ sum1, const float* __restrict__ ss1,
    const float* __restrict__ sum2, const float* __restrict__ ss2,
    void* __restrict__ out, const int* __restrict__ flag){
    __shared__ __align__(16) us sT[9*1152];
    __shared__ float scs[9], shs[9];
    int isf = *flag;
    int bid = blockIdx.x;
    int half = bid&1, c = (bid>>1)&63, b = bid>>7;
    int yy0 = half*24;
    int tid = threadIdx.x;
    if(tid < 9){
        int f = 9*c + tid;
        float sraw, qraw, gg, bb2;
        if(f < 64){ sraw = sum2[f]; qraw = ss2[f]; gg = ldx(gn,f,isf);  bb2 = ldx(bnb,f,isf); }
        else      { sraw = sum1[f]; qraw = ss1[f]; gg = ldx(gm,f,isf);  bb2 = ldx(bm,f,isf); }
        float mm  = sraw*INV_NCH;
        float ist = rsqrtf(qraw*INV_NCH - mm*mm + 1e-5f);
        float sc = ist*gg;
        scs[tid] = sc;
        shs[tid] = bb2 - mm*sc;
    }
    for(int t=tid; t<9*144; t+=256){
        int j = t/144, qq = t%144;
        int f = 9*c + j;
        const us* srcp = ((f<64) ? att   + (size_t)(b*64 +f)*SP
                                 : mixed + (size_t)(b*576+f)*SP) + yy0*48;
        ((uint4*)&sT[j*1152])[qq] = ((const uint4*)srcp)[qq];
    }
    __syncthreads();
    size_t pbase = (size_t)(b*64+c)*HH*WW;
    for(int t=tid; t<1296; t+=256){
        int Yl = t/18;
        int Xb = (t%18)*8;
        int yyl = Yl/3, r = Yl%3;
        float vo[8];
        #pragma unroll
        for(int k=0;k<8;++k){
            int X = Xb+k;
            int xx = X/3, sph = X%3;
            int j = 3*r + sph;
            float raw = us2f(sT[j*1152 + yyl*48 + xx]);
            float v = raw*scs[j] + shs[j];
            vo[k] = 1.f/(1.f + __expf(-v));
        }
        size_t off = pbase + (size_t)(yy0*3 + Yl)*WW + Xb;
        if(isf){
            const float4* xp = (const float4*)((const float*)x + off);
            float4 x0 = xp[0], x1 = xp[1];
            float4 o0, o1;
            o0.x = x0.x*vo[0]; o0.y = x0.y*vo[1]; o0.z = x0.z*vo[2]; o0.w = x0.w*vo[3];
            o1.x = x1.x*vo[4]; o1.y = x1.y*vo[5]; o1.z = x1.z*vo[6]; o1.w = x1.w*vo[7];
            float4* op = (float4*)((float*)out + off);
            op[0] = o0; op[1] = o1;
        } else {
            uint4 xr = *(const uint4*)((const us*)x + off);
            const us* xu = (const us*)&xr;
            union { us u[8]; uint4 v; } pk;
            #pragma unroll
            for(int k=0;k<8;++k)
                pk.u[k] = bfbits(us2f(xu[k])*vo[k]);
            *(uint4*)((us*)out + off) = pk.v;
        }
    }
}

// ===========================================================================

extern "C" void kernel_launch(void* const* d_in, const int* in_sizes, int n_in,
                              void* d_out, int out_size, void* d_ws, size_t ws_size,
                              hipStream_t stream) {
    (void)in_sizes; (void)n_in; (void)out_size; (void)ws_size;
    const void* x    = d_in[0];
    const void* wmix = d_in[1];
    const void* gm   = d_in[2];
    const void* bm   = d_in[3];
    const void* wh1  = d_in[4];
    const void* wv1  = d_in[5];
    const void* wh2  = d_in[6];
    const void* wv2  = d_in[7];
    const void* gn   = d_in[8];
    const void* bnb  = d_in[9];

    us* pf = (us*)d_out;          // focus-layout pool in d_out (dead before final)
    char* ws = (char*)d_ws;
    us*    mixed = (us*)   (ws + 0);           // 42467328 B
    us*    att   = (us*)   (ws + 42467328);    //  4718592 B
    float* st1a  = (float*)(ws + 47185920);    // raw sum1 (576)
    float* st1b  = (float*)(ws + 47188224);    // raw ss1  (576)
    float* st2a  = (float*)(ws + 47190528);    // raw sum2 (64)
    float* st2b  = (float*)(ws + 47190784);    // raw ss2  (64)
    int*   flag  = (int*)  (ws + 47191040);

    k_init  <<<1, 256, 0, stream>>>((const unsigned int*)x, flag, st1a);
    k_pool3 <<<BB*CC*9, 256, 0, stream>>>(x, pf, flag);
    k_mix3  <<<BB*9*8, 256, 0, stream>>>(pf, wmix, mixed, st1a, st1b, flag);
    k_conv3 <<<BB*64, 256, 0, stream>>>(mixed, st1a, st1b, gm, bm,
                                        wh1, wv1, wh2, wv2, att, st2a, st2b, flag);
    k_final3<<<BB*CC*2, 256, 0, stream>>>(x, mixed, att, gm, bm, gn, bnb,
                                          st1a, st1b, st2a, st2b, d_out, flag);
}

// Round 2
// 260.531 us; speedup vs baseline: 1.1094x; 1.1094x over previous
//
#include <hip/hip_runtime.h>
#include <hip/hip_bf16.h>

typedef __hip_bfloat16 bf16;
typedef unsigned short us;
typedef __attribute__((ext_vector_type(8))) short short8;
typedef __attribute__((ext_vector_type(4))) float floatx4;

__device__ __forceinline__ float b2f(bf16 v){ return __bfloat162float(v); }
__device__ __forceinline__ bf16  f2b(float v){ return __float2bfloat16(v); }
__device__ __forceinline__ float ldx(const void* p, size_t i, int isf){
    return isf ? ((const float*)p)[i] : b2f(((const bf16*)p)[i]);
}
__device__ __forceinline__ us bfbits(float v){
    bf16 h = f2b(v); return *(us*)&h;
}
__device__ __forceinline__ float us2f(us u){
    unsigned int w = ((unsigned int)u)<<16; float f; __builtin_memcpy(&f,&w,4); return f;
}

#define BB   16
#define CC   64
#define HH   144
#define WW   144
#define HS   48
#define SP   (HS*HS)            // 2304
#define NTOT (BB*CC*HH*WW)      // 21233664
#define NCH  36864              // B*SP
#define INV_NCH (1.f/36864.f)

// -------- 0. init: dtype sniff + zero stats --------------------------------
__global__ void k_init(const unsigned int* __restrict__ x, int* __restrict__ flag,
                       float* __restrict__ stats){
    for(int i=threadIdx.x; i<1280; i+=256) stats[i] = 0.f;
    __shared__ int hit;
    if(threadIdx.x==0) hit = 0;
    __syncthreads();
    int local = 0;
    for(int t=threadIdx.x; t<4096; t+=256){
        unsigned int w = x[t];
        if(((w>>7)&0xFFu)==0xFFu || ((w>>23)&0xFFu)==0xFFu) local = 1;
    }
    if(local) atomicOr(&hit, 1);
    __syncthreads();
    if(threadIdx.x==0) *flag = hit;
}

// -------- 1. maxpool 3x3 s1 p1, writes FOCUS layout ------------------------
// pf[b][gi][gj][c][y][xx] = maxpool(x)[b,c,3y+gi,3xx+gj]
__global__ __launch_bounds__(256) void k_pool3(const void* __restrict__ x,
                                               us* __restrict__ pf,
                                               const int* __restrict__ flag){
    __shared__ float l [18*148];
    __shared__ float hm[18*148];
    int isf = *flag;
    int bid = blockIdx.x;
    int strip = bid % 9;
    int bc = bid / 9;
    int b = bc>>6, c = bc&63;
    int r0 = strip*16;
    size_t base = (size_t)bc*HH*WW;
    int tid = threadIdx.x;
    // load rows r0-1 .. r0+16 (18 rows x 144), 8-wide vectors
    for(int t=tid; t<18*18; t+=256){
        int row = t/18, ch = t%18;
        int rr = r0-1+row; int c0 = ch*8;
        float v[8];
        if(rr>=0 && rr<HH){
            if(isf){
                const float* xp = (const float*)x + base + (size_t)rr*WW + c0;
                float4 f0 = *(const float4*)xp;
                float4 f1 = *(const float4*)(xp+4);
                v[0]=f0.x;v[1]=f0.y;v[2]=f0.z;v[3]=f0.w;
                v[4]=f1.x;v[5]=f1.y;v[6]=f1.z;v[7]=f1.w;
            } else {
                const us* xp = (const us*)x + base + (size_t)rr*WW + c0;
                uint4 d = *(const uint4*)xp;
                const us* u = (const us*)&d;
                #pragma unroll
                for(int e=0;e<8;++e) v[e] = us2f(u[e]);
            }
        } else {
            #pragma unroll
            for(int e=0;e<8;++e) v[e] = -INFINITY;
        }
        #pragma unroll
        for(int e=0;e<8;++e) l[row*148 + c0 + e] = v[e];
    }
    __syncthreads();
    for(int t=tid; t<18*144; t+=256){
        int row = t/144, cc = t%144;
        float a = l[row*148+cc];
        float bb = (cc>0)   ? l[row*148+cc-1] : -INFINITY;
        float cv = (cc<143) ? l[row*148+cc+1] : -INFINITY;
        hm[row*148+cc] = fmaxf(a, fmaxf(bb,cv));
    }
    __syncthreads();
    // vmax + scatter to focus layout; 4 outputs (same gj) per iter
    for(int t=tid; t<576; t+=256){
        int row = t/36;
        int gj  = (t/12)%3;
        int xg  = t%12;
        int R = r0+row;
        int gi = R%3, y = R/3;
        union { us u[4]; uint2 v; } pk;
        #pragma unroll
        for(int e=0;e<4;++e){
            int xx = xg*4+e; int C = 3*xx+gj;
            float m = fmaxf(hm[row*148+C],
                      fmaxf(hm[(row+1)*148+C], hm[(row+2)*148+C]));
            pk.u[e] = bfbits(m);
        }
        size_t o = ((((size_t)(b*3+gi)*3+gj)*64 + c)*48 + y)*48 + xg*4;
        *(uint2*)&pf[o] = pk.v;
    }
}

// -------- 2. MFMA mixer + BN1 stats ----------------------------------------
// block = (b,g,chunk): C[64 o][288 sites] = W_g[64x64] x I[64x288]
// LDS swizzle: element (row, i) at row*64 + ((i/8 + row)%8)*8 + i%8
__global__ __launch_bounds__(256) void k_mix3(const us* __restrict__ pf,
        const void* __restrict__ wmix, us* __restrict__ mixed,
        float* __restrict__ sum1, float* __restrict__ ss1,
        const int* __restrict__ flag){
    __shared__ __align__(16) us sW[4096];
    __shared__ __align__(16) us sI[288*64];
    __shared__ float sS[64], sQ[64];
    int isf = *flag;
    int bid = blockIdx.x;
    int chunk = bid%8, g = (bid/8)%9, b = bid/72;
    int gi = g/3, gj = g%3;
    int tid = threadIdx.x, lane = tid&63, w = tid>>6;
    // stage W (swizzled): thread -> o=tid/4, i-range 16
    {
        int o  = tid>>2;
        int i0 = (tid&3)*16;
        #pragma unroll
        for(int e=0;e<16;++e){
            int i = i0+e;
            float v = ldx(wmix, (size_t)g*4096 + (size_t)o*64 + i, isf);
            sW[o*64 + ((((i>>3)+o)&7)<<3) + (i&7)] = bfbits(v);
        }
    }
    if(tid<64){ sS[tid]=0.f; sQ[tid]=0.f; }
    // stage I (swizzled): lane = channel i, wave covers 9 vec8 chunks
    {
        int i = lane;
        const us* src = pf + ((((size_t)(b*3+gi)*3+gj)*64 + i)*48 + (size_t)chunk*6)*48;
        for(int vv=w*9; vv<(w+1)*9; ++vv){
            uint4 d = *(const uint4*)(src + vv*8);
            const us* u = (const us*)&d;
            #pragma unroll
            for(int e=0;e<8;++e){
                int s = vv*8+e;
                sI[s*64 + ((((i>>3)+s)&7)<<3) + (i&7)] = u[e];
            }
        }
    }
    __syncthreads();
    int n = lane&15, quad = lane>>4;
    int m = w*16 + n;   // this wave's A rows (o)
    // A fragments for k0=0 (q2=quad) and k0=32 (q2=4+quad)
    short8 a0 = *(const short8*)&sW[m*64 + (((quad     + m)&7)<<3)];
    short8 a1 = *(const short8*)&sW[m*64 + ((((4+quad) + m)&7)<<3)];
    floatx4 acc[18];
    #pragma unroll
    for(int nt=0; nt<18; ++nt) acc[nt] = (floatx4){0.f,0.f,0.f,0.f};
    #pragma unroll
    for(int nt=0; nt<18; ++nt){
        int site = nt*16 + n;
        short8 b0 = *(const short8*)&sI[site*64 + (((quad     + site)&7)<<3)];
        short8 b1 = *(const short8*)&sI[site*64 + ((((4+quad) + site)&7)<<3)];
        acc[nt] = __builtin_amdgcn_mfma_f32_16x16x32_bf16(a0, b0, acc[nt], 0,0,0);
        acc[nt] = __builtin_amdgcn_mfma_f32_16x16x32_bf16(a1, b1, acc[nt], 0,0,0);
    }
    // store + per-lane stats.  C layout: col=lane&15 (site), row=quad*4+r (o)
    size_t obase = (size_t)(b*576 + g*64)*SP + (size_t)chunk*288;
    float s[4] = {0,0,0,0}, q[4] = {0,0,0,0};
    #pragma unroll
    for(int nt=0; nt<18; ++nt){
        #pragma unroll
        for(int r=0;r<4;++r){
            float v = acc[nt][r];
            int o = w*16 + quad*4 + r;
            mixed[obase + (size_t)o*SP + nt*16 + n] = bfbits(v);
            s[r] += v; q[r] += v*v;
        }
    }
    #pragma unroll
    for(int off=1; off<=8; off<<=1){
        #pragma unroll
        for(int r=0;r<4;++r){
            s[r] += __shfl_xor(s[r], off, 64);
            q[r] += __shfl_xor(q[r], off, 64);
        }
    }
    if(n==0){
        #pragma unroll
        for(int r=0;r<4;++r){
            atomicAdd(&sS[w*16+quad*4+r], s[r]);
            atomicAdd(&sQ[w*16+quad*4+r], q[r]);
        }
    }
    __syncthreads();
    if(tid<64){
        atomicAdd(&sum1[g*64+tid], sS[tid]);
        atomicAdd(&ss1 [g*64+tid], sQ[tid]);
    }
}

// -------- 3. fused 4-way depthwise conv + BN1 inline + BN2 stats -----------
// Scalar output mapping (w = t%48, lane-contiguous -> conflict-free).
// conv3 (taps [h+u][w+v-u]) and conv4 (taps [h+v-u][w+u]) share windows, so
// their weights merge into one 13x3 table w34 (zero-padded at |r|=6).
// All 105 weights are copied to REGISTERS once per thread, so the inner loop
// is pure {ds_read_b32 imm-offset + v_fmac}; weight LDS traffic ~0.
__global__ __launch_bounds__(256) void k_conv3(const us* __restrict__ mixed,
    const float* __restrict__ sum1, const float* __restrict__ ss1,
    const void* __restrict__ gm, const void* __restrict__ bm,
    const void* __restrict__ wh1, const void* __restrict__ wv1,
    const void* __restrict__ wh2, const void* __restrict__ wv2,
    us* __restrict__ att, float* __restrict__ sum2, float* __restrict__ ss2,
    const int* __restrict__ flag){
    __shared__ float tile[60*60+4];
    __shared__ float w1[33], w2[33], w34[39];
    __shared__ float r1[256], r2[256];
    int isf = *flag;
    int bid = blockIdx.x;
    int b = bid/64, c = bid%64;
    int tid = threadIdx.x;
    for(int t=tid; t<3604; t+=256) tile[t] = 0.f;
    if(tid < 33){
        w1[tid] = ldx(wh1, c*33 + tid, isf);
    } else if(tid < 66){
        w2[tid-33] = ldx(wv1, c*33 + (tid-33), isf);
    } else if(tid < 105){
        int k = tid-66;            // 0..38 : 13 rows x 3
        int r = k/3 - 6;           // row offset -6..6
        int vo = k%3 - 1;          // original v  -1..1
        float a = 0.f;
        if(r >= -5 && r <= 5)      // conv3 (h-transform), u = r
            a += ldx(wh2, c*33 + (r+5)*3 + (vo+1), isf);
        int u = vo - r;            // conv4 (v-transform), row off = vo-u
        if(u >= -5 && u <= 5)
            a += ldx(wv2, c*33 + (vo+1)*11 + (u+5), isf);
        w34[k] = a;
    }
    __syncthreads();
    // BN1 params for this channel (computed from raw sums — finstats folded in)
    float mu   = sum1[c]*INV_NCH;
    float var  = ss1[c]*INV_NCH - mu*mu;
    float is   = rsqrtf(var + 1e-5f)*ldx(gm,c,isf);
    float be   = ldx(bm,c,isf);
    const us* src = mixed + (size_t)(b*576 + c)*SP;
    // weights -> registers (compile-time indexed after unroll)
    float w1r[33], w2r[33], w34r[39];
    #pragma unroll
    for(int i=0;i<33;++i) w1r[i] = w1[i];
    #pragma unroll
    for(int i=0;i<33;++i) w2r[i] = w2[i];
    #pragma unroll
    for(int i=0;i<39;++i) w34r[i] = w34[i];
    for(int t=tid; t<288; t+=256){
        int h = t/6, w0 = (t%6)*8;
        uint4 d = *(const uint4*)(src + t*8);
        const us* u = (const us*)&d;
        #pragma unroll
        for(int e=0;e<8;++e)
            tile[(h+6)*60 + (w0+6) + e] = (us2f(u[e]) - mu)*is + be;
    }
    __syncthreads();
    us* out = att + (size_t)(b*64 + c)*SP;
    float sl = 0.f, ql = 0.f;
    #pragma unroll 1
    for(int it=0; it<9; ++it){
        int t = it*256 + tid;               // 2304 = 9*256, no tail
        int hh = t/48 + 6, w = t%48 + 6;    // lanes contiguous in w
        const float* bp = &tile[hh*60 + w];
        float acc = 0.f;
        // conv2 (3x11)
        #pragma unroll
        for(int r=-1; r<=1; ++r)
            #pragma unroll
            for(int v=-5; v<=5; ++v)
                acc += w2r[(r+1)*11 + (v+5)] * bp[r*60 + v];
        // conv1 (11x3)
        #pragma unroll
        for(int r=-5; r<=5; ++r)
            #pragma unroll
            for(int v=-1; v<=1; ++v)
                acc += w1r[(r+5)*3 + (v+1)] * bp[r*60 + v];
        // merged conv3+conv4 (13x3 diagonal)
        #pragma unroll
        for(int r=-6; r<=6; ++r)
            #pragma unroll
            for(int v=-1; v<=1; ++v)
                acc += w34r[(r+6)*3 + (v+1)] * bp[r*60 + (v-r)];
        out[t] = bfbits(acc);
        sl += acc; ql += acc*acc;
    }
    r1[tid]=sl; r2[tid]=ql; __syncthreads();
    for(int o=128;o>0;o>>=1){
        if(tid<o){ r1[tid]+=r1[tid+o]; r2[tid]+=r2[tid+o]; }
        __syncthreads();
    }
    if(tid==0){
        atomicAdd(&sum2[c], r1[0]);
        atomicAdd(&ss2 [c], r2[0]);
    }
}

// -------- 4. final: BN + pixel_shuffle + sigmoid gate (y-split) ------------
__global__ __launch_bounds__(256) void k_final3(const void* __restrict__ x,
    const us* __restrict__ mixed, const us* __restrict__ att,
    const void* __restrict__ gm, const void* __restrict__ bm,
    const void* __restrict__ gn, const void* __restrict__ bnb,
    const float* __restrict__ sum1, const float* __restrict__ ss1,
    const float* __restrict__ sum2, const float* __restrict__ ss2,
    void* __restrict__ out, const int* __restrict__ flag){
    __shared__ __align__(16) us sT[9*1152];
    __shared__ float scs[9], shs[9];
    int isf = *flag;
    int bid = blockIdx.x;
    int half = bid&1, c = (bid>>1)&63, b = bid>>7;
    int yy0 = half*24;
    int tid = threadIdx.x;
    if(tid < 9){
        int f = 9*c + tid;
        float sraw, qraw, gg, bb2;
        if(f < 64){ sraw = sum2[f]; qraw = ss2[f]; gg = ldx(gn,f,isf);  bb2 = ldx(bnb,f,isf); }
        else      { sraw = sum1[f]; qraw = ss1[f]; gg = ldx(gm,f,isf);  bb2 = ldx(bm,f,isf); }
        float mm  = sraw*INV_NCH;
        float ist = rsqrtf(qraw*INV_NCH - mm*mm + 1e-5f);
        float sc = ist*gg;
        scs[tid] = sc;
        shs[tid] = bb2 - mm*sc;
    }
    for(int t=tid; t<9*144; t+=256){
        int j = t/144, qq = t%144;
        int f = 9*c + j;
        const us* srcp = ((f<64) ? att   + (size_t)(b*64 +f)*SP
                                 : mixed + (size_t)(b*576+f)*SP) + yy0*48;
        ((uint4*)&sT[j*1152])[qq] = ((const uint4*)srcp)[qq];
    }
    __syncthreads();
    size_t pbase = (size_t)(b*64+c)*HH*WW;
    for(int t=tid; t<1296; t+=256){
        int Yl = t/18;
        int Xb = (t%18)*8;
        int yyl = Yl/3, r = Yl%3;
        float vo[8];
        #pragma unroll
        for(int k=0;k<8;++k){
            int X = Xb+k;
            int xx = X/3, sph = X%3;
            int j = 3*r + sph;
            float raw = us2f(sT[j*1152 + yyl*48 + xx]);
            float v = raw*scs[j] + shs[j];
            vo[k] = 1.f/(1.f + __expf(-v));
        }
        size_t off = pbase + (size_t)(yy0*3 + Yl)*WW + Xb;
        if(isf){
            const float4* xp = (const float4*)((const float*)x + off);
            float4 x0 = xp[0], x1 = xp[1];
            float4 o0, o1;
            o0.x = x0.x*vo[0]; o0.y = x0.y*vo[1]; o0.z = x0.z*vo[2]; o0.w = x0.w*vo[3];
            o1.x = x1.x*vo[4]; o1.y = x1.y*vo[5]; o1.z = x1.z*vo[6]; o1.w = x1.w*vo[7];
            float4* op = (float4*)((float*)out + off);
            op[0] = o0; op[1] = o1;
        } else {
            uint4 xr = *(const uint4*)((const us*)x + off);
            const us* xu = (const us*)&xr;
            union { us u[8]; uint4 v; } pk;
            #pragma unroll
            for(int k=0;k<8;++k)
                pk.u[k] = bfbits(us2f(xu[k])*vo[k]);
            *(uint4*)((us*)out + off) = pk.v;
        }
    }
}

// ===========================================================================

extern "C" void kernel_launch(void* const* d_in, const int* in_sizes, int n_in,
                              void* d_out, int out_size, void* d_ws, size_t ws_size,
                              hipStream_t stream) {
    (void)in_sizes; (void)n_in; (void)out_size; (void)ws_size;
    const void* x    = d_in[0];
    const void* wmix = d_in[1];
    const void* gm   = d_in[2];
    const void* bm   = d_in[3];
    const void* wh1  = d_in[4];
    const void* wv1  = d_in[5];
    const void* wh2  = d_in[6];
    const void* wv2  = d_in[7];
    const void* gn   = d_in[8];
    const void* bnb  = d_in[9];

    us* pf = (us*)d_out;          // focus-layout pool in d_out (dead before final)
    char* ws = (char*)d_ws;
    us*    mixed = (us*)   (ws + 0);           // 42467328 B
    us*    att   = (us*)   (ws + 42467328);    //  4718592 B
    float* st1a  = (float*)(ws + 47185920);    // raw sum1 (576)
    float* st1b  = (float*)(ws + 47188224);    // raw ss1  (576)
    float* st2a  = (float*)(ws + 47190528);    // raw sum2 (64)
    float* st2b  = (float*)(ws + 47190784);    // raw ss2  (64)
    int*   flag  = (int*)  (ws + 47191040);

    k_init  <<<1, 256, 0, stream>>>((const unsigned int*)x, flag, st1a);
    k_pool3 <<<BB*CC*9, 256, 0, stream>>>(x, pf, flag);
    k_mix3  <<<BB*9*8, 256, 0, stream>>>(pf, wmix, mixed, st1a, st1b, flag);
    k_conv3 <<<BB*64, 256, 0, stream>>>(mixed, st1a, st1b, gm, bm,
                                        wh1, wv1, wh2, wv2, att, st2a, st2b, flag);
    k_final3<<<BB*CC*2, 256, 0, stream>>>(x, mixed, att, gm, bm, gn, bnb,
                                          st1a, st1b, st2a, st2b, d_out, flag);
}

// Round 3
// 250.918 us; speedup vs baseline: 1.1519x; 1.0383x over previous
//
#include <hip/hip_runtime.h>
#include <hip/hip_bf16.h>

typedef __hip_bfloat16 bf16;
typedef unsigned short us;
typedef __attribute__((ext_vector_type(8))) short short8;
typedef __attribute__((ext_vector_type(4))) float floatx4;

__device__ __forceinline__ float b2f(bf16 v){ return __bfloat162float(v); }
__device__ __forceinline__ bf16  f2b(float v){ return __float2bfloat16(v); }
__device__ __forceinline__ float ldx(const void* p, size_t i, int isf){
    return isf ? ((const float*)p)[i] : b2f(((const bf16*)p)[i]);
}
__device__ __forceinline__ us bfbits(float v){
    bf16 h = f2b(v); return *(us*)&h;
}
__device__ __forceinline__ float us2f(us u){
    unsigned int w = ((unsigned int)u)<<16; float f; __builtin_memcpy(&f,&w,4); return f;
}

#define BB   16
#define CC   64
#define HH   144
#define WW   144
#define HS   48
#define SP   (HS*HS)            // 2304
#define NTOT (BB*CC*HH*WW)      // 21233664
#define NCH  36864              // B*SP
#define INV_NCH (1.f/36864.f)

// TISF: 1 = f32, 0 = bf16, -1 = resolve from device flag (sniffer fallback)
template<int TISF>
__device__ __forceinline__ int isf_of(const int* flag){
    if(TISF >= 0) return TISF;
    return *flag;
}

// -------- 0. dtype sniffer (fallback only) ---------------------------------
__global__ void k_sniff(const unsigned int* __restrict__ x, int* __restrict__ flag){
    __shared__ int hit;
    if(threadIdx.x==0) hit = 0;
    __syncthreads();
    int local = 0;
    for(int t=threadIdx.x; t<4096; t+=256){
        unsigned int w = x[t];
        if(((w>>7)&0xFFu)==0xFFu || ((w>>23)&0xFFu)==0xFFu) local = 1;
    }
    if(local) atomicOr(&hit, 1);
    __syncthreads();
    if(threadIdx.x==0) *flag = hit;
}

// -------- 1. maxpool 3x3 s1 p1, writes FOCUS layout (+ stats zeroing) ------
// pf[b][gi][gj][c][y][xx] = maxpool(x)[b,c,3y+gi,3xx+gj]
template<int TISF>
__global__ __launch_bounds__(256) void k_pool3(const void* __restrict__ x,
                                               us* __restrict__ pf,
                                               const int* __restrict__ flag,
                                               float* __restrict__ stats){
    __shared__ float l [18*148];
    __shared__ float hm[18*148];
    int isf = isf_of<TISF>(flag);
    int bid = blockIdx.x;
    int tid = threadIdx.x;
    if(bid==0){                        // zero BN stat accumulators (pre-mix3)
        for(int i=tid; i<1280; i+=256) stats[i] = 0.f;
    }
    int strip = bid % 9;
    int bc = bid / 9;
    int b = bc>>6, c = bc&63;
    int r0 = strip*16;
    size_t base = (size_t)bc*HH*WW;
    // load rows r0-1 .. r0+16 (18 rows x 144), 8-wide vectors
    for(int t=tid; t<18*18; t+=256){
        int row = t/18, ch = t%18;
        int rr = r0-1+row; int c0 = ch*8;
        float v[8];
        if(rr>=0 && rr<HH){
            if(isf){
                const float* xp = (const float*)x + base + (size_t)rr*WW + c0;
                float4 f0 = *(const float4*)xp;
                float4 f1 = *(const float4*)(xp+4);
                v[0]=f0.x;v[1]=f0.y;v[2]=f0.z;v[3]=f0.w;
                v[4]=f1.x;v[5]=f1.y;v[6]=f1.z;v[7]=f1.w;
            } else {
                const us* xp = (const us*)x + base + (size_t)rr*WW + c0;
                uint4 d = *(const uint4*)xp;
                const us* u = (const us*)&d;
                #pragma unroll
                for(int e=0;e<8;++e) v[e] = us2f(u[e]);
            }
        } else {
            #pragma unroll
            for(int e=0;e<8;++e) v[e] = -INFINITY;
        }
        #pragma unroll
        for(int e=0;e<8;++e) l[row*148 + c0 + e] = v[e];
    }
    __syncthreads();
    for(int t=tid; t<18*144; t+=256){
        int row = t/144, cc = t%144;
        float a = l[row*148+cc];
        float bb = (cc>0)   ? l[row*148+cc-1] : -INFINITY;
        float cv = (cc<143) ? l[row*148+cc+1] : -INFINITY;
        hm[row*148+cc] = fmaxf(a, fmaxf(bb,cv));
    }
    __syncthreads();
    // vmax + scatter to focus layout; 4 outputs (same gj) per iter
    for(int t=tid; t<576; t+=256){
        int row = t/36;
        int gj  = (t/12)%3;
        int xg  = t%12;
        int R = r0+row;
        int gi = R%3, y = R/3;
        union { us u[4]; uint2 v; } pk;
        #pragma unroll
        for(int e=0;e<4;++e){
            int xx = xg*4+e; int C = 3*xx+gj;
            float m = fmaxf(hm[row*148+C],
                      fmaxf(hm[(row+1)*148+C], hm[(row+2)*148+C]));
            pk.u[e] = bfbits(m);
        }
        size_t o = ((((size_t)(b*3+gi)*3+gj)*64 + c)*48 + y)*48 + xg*4;
        *(uint2*)&pf[o] = pk.v;
    }
}

// -------- 2. MFMA mixer + BN1 stats ----------------------------------------
// block = (b,g,chunk): C[64 o][288 sites] = W_g[64x64] x I[64x288]
// LDS swizzle: element (row, i) at row*64 + ((i/8 + row)%8)*8 + i%8
// Epilogue: per-wave 16x40-us LDS transpose -> coalesced dwordx4 stores.
template<int TISF>
__global__ __launch_bounds__(256) void k_mix3(const us* __restrict__ pf,
        const void* __restrict__ wmix, us* __restrict__ mixed,
        float* __restrict__ sum1, float* __restrict__ ss1,
        const int* __restrict__ flag){
    __shared__ __align__(16) us sAll[4096 + 288*64];   // sW | sI (sW reused as scratch)
    __shared__ float sS[64], sQ[64];
    us* sW = sAll;
    us* sI = sAll + 4096;
    int isf = isf_of<TISF>(flag);
    int bid = blockIdx.x;
    int chunk = bid%8, g = (bid/8)%9, b = bid/72;
    int gi = g/3, gj = g%3;
    int tid = threadIdx.x, lane = tid&63, w = tid>>6;
    // stage W (swizzled), vectorized global loads: thread -> o=tid/4, i-range 16
    {
        int o  = tid>>2;
        int i0 = (tid&3)*16;
        us wb[16];
        if(isf){
            const float* wp = (const float*)wmix + (size_t)g*4096 + (size_t)o*64 + i0;
            #pragma unroll
            for(int e=0;e<16;e+=4){
                float4 f = *(const float4*)(wp+e);
                wb[e]=bfbits(f.x); wb[e+1]=bfbits(f.y);
                wb[e+2]=bfbits(f.z); wb[e+3]=bfbits(f.w);
            }
        } else {
            const us* wp = (const us*)wmix + (size_t)g*4096 + (size_t)o*64 + i0;
            uint4 d0 = *(const uint4*)wp, d1 = *(const uint4*)(wp+8);
            const us* u0 = (const us*)&d0; const us* u1 = (const us*)&d1;
            #pragma unroll
            for(int e=0;e<8;++e){ wb[e]=u0[e]; wb[8+e]=u1[e]; }
        }
        #pragma unroll
        for(int e=0;e<16;++e){
            int i = i0+e;
            sW[o*64 + ((((i>>3)+o)&7)<<3) + (i&7)] = wb[e];
        }
    }
    if(tid<64){ sS[tid]=0.f; sQ[tid]=0.f; }
    // stage I (swizzled): lane = channel i, wave covers 9 vec8 chunks
    {
        int i = lane;
        const us* src = pf + ((((size_t)(b*3+gi)*3+gj)*64 + i)*48 + (size_t)chunk*6)*48;
        for(int vv=w*9; vv<(w+1)*9; ++vv){
            uint4 d = *(const uint4*)(src + vv*8);
            const us* u = (const us*)&d;
            #pragma unroll
            for(int e=0;e<8;++e){
                int s = vv*8+e;
                sI[s*64 + ((((i>>3)+s)&7)<<3) + (i&7)] = u[e];
            }
        }
    }
    __syncthreads();
    int n = lane&15, quad = lane>>4;
    int m = w*16 + n;   // this wave's A rows (o)
    // A fragments for k0=0 (q2=quad) and k0=32 (q2=4+quad)
    short8 a0 = *(const short8*)&sW[m*64 + (((quad     + m)&7)<<3)];
    short8 a1 = *(const short8*)&sW[m*64 + ((((4+quad) + m)&7)<<3)];
    floatx4 acc[18];
    #pragma unroll
    for(int nt=0; nt<18; ++nt) acc[nt] = (floatx4){0.f,0.f,0.f,0.f};
    #pragma unroll
    for(int nt=0; nt<18; ++nt){
        int site = nt*16 + n;
        short8 b0 = *(const short8*)&sI[site*64 + (((quad     + site)&7)<<3)];
        short8 b1 = *(const short8*)&sI[site*64 + ((((4+quad) + site)&7)<<3)];
        acc[nt] = __builtin_amdgcn_mfma_f32_16x16x32_bf16(a0, b0, acc[nt], 0,0,0);
        acc[nt] = __builtin_amdgcn_mfma_f32_16x16x32_bf16(a1, b1, acc[nt], 0,0,0);
    }
    // per-lane stats.  C layout: col=lane&15 (site), row=quad*4+r (o)
    float s[4] = {0,0,0,0}, q[4] = {0,0,0,0};
    #pragma unroll
    for(int nt=0; nt<18; ++nt){
        #pragma unroll
        for(int r=0;r<4;++r){
            float v = acc[nt][r];
            s[r] += v; q[r] += v*v;
        }
    }
    #pragma unroll
    for(int off=1; off<=8; off<<=1){
        #pragma unroll
        for(int r=0;r<4;++r){
            s[r] += __shfl_xor(s[r], off, 64);
            q[r] += __shfl_xor(q[r], off, 64);
        }
    }
    if(n==0){
        #pragma unroll
        for(int r=0;r<4;++r){
            atomicAdd(&sS[w*16+quad*4+r], s[r]);
            atomicAdd(&sQ[w*16+quad*4+r], q[r]);
        }
    }
    __syncthreads();   // also guarantees all waves done with sW/sI reads
    if(tid<64){
        atomicAdd(&sum1[g*64+tid], sS[tid]);
        atomicAdd(&ss1 [g*64+tid], sQ[tid]);
    }
    // ---- transpose epilogue: per-wave 16x40-us scratch in sW region -------
    // acc[nt][r] = C[o = w*16+quad*4+r][site = nt*16+n]
    us* swr = sAll + w*640;           // 16 rows x 40 us per wave (1280 B)
    int o_loc = lane>>2, s8 = (lane&3)*8;
    size_t rowbase = ((size_t)(b*576 + g*64 + w*16))*SP + (size_t)chunk*288;
    #pragma unroll
    for(int mp=0; mp<9; ++mp){
        __builtin_amdgcn_wave_barrier();
        #pragma unroll
        for(int half=0; half<2; ++half){
            int nt = mp*2 + half;
            #pragma unroll
            for(int r=0;r<4;++r)
                swr[(quad*4+r)*40 + half*16 + n] = bfbits(acc[nt][r]);
        }
        __builtin_amdgcn_wave_barrier();
        uint4 vv = *(const uint4*)&swr[o_loc*40 + s8];
        *(uint4*)&mixed[rowbase + (size_t)o_loc*SP + (size_t)(mp*32 + s8)] = vv;
    }
}

// -------- 3. fused 4-way depthwise conv + BN1 inline + BN2 stats -----------
// Scalar output mapping (w = t%48, lane-contiguous -> conflict-free).
// conv3/conv4 weights merged into one 13x3 table w34 (zero-padded at |r|=6).
// All 105 weights in REGISTERS; inner loop pure {ds_read imm-offset + fmac}.
template<int TISF>
__global__ __launch_bounds__(256) void k_conv3(const us* __restrict__ mixed,
    const float* __restrict__ sum1, const float* __restrict__ ss1,
    const void* __restrict__ gm, const void* __restrict__ bm,
    const void* __restrict__ wh1, const void* __restrict__ wv1,
    const void* __restrict__ wh2, const void* __restrict__ wv2,
    us* __restrict__ att, float* __restrict__ sum2, float* __restrict__ ss2,
    const int* __restrict__ flag){
    __shared__ float tile[60*60+4];
    __shared__ float w1[33], w2[33], w34[39];
    __shared__ float r1[256], r2[256];
    int isf = isf_of<TISF>(flag);
    int bid = blockIdx.x;
    int b = bid/64, c = bid%64;
    int tid = threadIdx.x;
    for(int t=tid; t<3604; t+=256) tile[t] = 0.f;
    if(tid < 33){
        w1[tid] = ldx(wh1, c*33 + tid, isf);
    } else if(tid < 66){
        w2[tid-33] = ldx(wv1, c*33 + (tid-33), isf);
    } else if(tid < 105){
        int k = tid-66;            // 0..38 : 13 rows x 3
        int r = k/3 - 6;           // row offset -6..6
        int vo = k%3 - 1;          // original v  -1..1
        float a = 0.f;
        if(r >= -5 && r <= 5)      // conv3 (h-transform), u = r
            a += ldx(wh2, c*33 + (r+5)*3 + (vo+1), isf);
        int u = vo - r;            // conv4 (v-transform), row off = vo-u
        if(u >= -5 && u <= 5)
            a += ldx(wv2, c*33 + (vo+1)*11 + (u+5), isf);
        w34[k] = a;
    }
    __syncthreads();
    // BN1 params for this channel (computed from raw sums)
    float mu   = sum1[c]*INV_NCH;
    float var  = ss1[c]*INV_NCH - mu*mu;
    float is   = rsqrtf(var + 1e-5f)*ldx(gm,c,isf);
    float be   = ldx(bm,c,isf);
    const us* src = mixed + (size_t)(b*576 + c)*SP;
    // weights -> registers (compile-time indexed after unroll)
    float w1r[33], w2r[33], w34r[39];
    #pragma unroll
    for(int i=0;i<33;++i) w1r[i] = w1[i];
    #pragma unroll
    for(int i=0;i<33;++i) w2r[i] = w2[i];
    #pragma unroll
    for(int i=0;i<39;++i) w34r[i] = w34[i];
    for(int t=tid; t<288; t+=256){
        int h = t/6, w0 = (t%6)*8;
        uint4 d = *(const uint4*)(src + t*8);
        const us* u = (const us*)&d;
        #pragma unroll
        for(int e=0;e<8;++e)
            tile[(h+6)*60 + (w0+6) + e] = (us2f(u[e]) - mu)*is + be;
    }
    __syncthreads();
    us* out = att + (size_t)(b*64 + c)*SP;
    float sl = 0.f, ql = 0.f;
    #pragma unroll 1
    for(int it=0; it<9; ++it){
        int t = it*256 + tid;               // 2304 = 9*256, no tail
        int hh = t/48 + 6, w = t%48 + 6;    // lanes contiguous in w
        const float* bp = &tile[hh*60 + w];
        float acc = 0.f;
        // conv2 (3x11)
        #pragma unroll
        for(int r=-1; r<=1; ++r)
            #pragma unroll
            for(int v=-5; v<=5; ++v)
                acc += w2r[(r+1)*11 + (v+5)] * bp[r*60 + v];
        // conv1 (11x3)
        #pragma unroll
        for(int r=-5; r<=5; ++r)
            #pragma unroll
            for(int v=-1; v<=1; ++v)
                acc += w1r[(r+5)*3 + (v+1)] * bp[r*60 + v];
        // merged conv3+conv4 (13x3 diagonal)
        #pragma unroll
        for(int r=-6; r<=6; ++r)
            #pragma unroll
            for(int v=-1; v<=1; ++v)
                acc += w34r[(r+6)*3 + (v+1)] * bp[r*60 + (v-r)];
        out[t] = bfbits(acc);
        sl += acc; ql += acc*acc;
    }
    r1[tid]=sl; r2[tid]=ql; __syncthreads();
    for(int o=128;o>0;o>>=1){
        if(tid<o){ r1[tid]+=r1[tid+o]; r2[tid]+=r2[tid+o]; }
        __syncthreads();
    }
    if(tid==0){
        atomicAdd(&sum2[c], r1[0]);
        atomicAdd(&ss2 [c], r2[0]);
    }
}

// -------- 4. final: BN + pixel_shuffle + sigmoid gate (y-split) ------------
template<int TISF>
__global__ __launch_bounds__(256) void k_final3(const void* __restrict__ x,
    const us* __restrict__ mixed, const us* __restrict__ att,
    const void* __restrict__ gm, const void* __restrict__ bm,
    const void* __restrict__ gn, const void* __restrict__ bnb,
    const float* __restrict__ sum1, const float* __restrict__ ss1,
    const float* __restrict__ sum2, const float* __restrict__ ss2,
    void* __restrict__ out, const int* __restrict__ flag){
    __shared__ __align__(16) us sT[9*1152];
    __shared__ float scs[9], shs[9];
    int isf = isf_of<TISF>(flag);
    int bid = blockIdx.x;
    int half = bid&1, c = (bid>>1)&63, b = bid>>7;
    int yy0 = half*24;
    int tid = threadIdx.x;
    if(tid < 9){
        int f = 9*c + tid;
        float sraw, qraw, gg, bb2;
        if(f < 64){ sraw = sum2[f]; qraw = ss2[f]; gg = ldx(gn,f,isf);  bb2 = ldx(bnb,f,isf); }
        else      { sraw = sum1[f]; qraw = ss1[f]; gg = ldx(gm,f,isf);  bb2 = ldx(bm,f,isf); }
        float mm  = sraw*INV_NCH;
        float ist = rsqrtf(qraw*INV_NCH - mm*mm + 1e-5f);
        float sc = ist*gg;
        scs[tid] = sc;
        shs[tid] = bb2 - mm*sc;
    }
    for(int t=tid; t<9*144; t+=256){
        int j = t/144, qq = t%144;
        int f = 9*c + j;
        const us* srcp = ((f<64) ? att   + (size_t)(b*64 +f)*SP
                                 : mixed + (size_t)(b*576+f)*SP) + yy0*48;
        ((uint4*)&sT[j*1152])[qq] = ((const uint4*)srcp)[qq];
    }
    __syncthreads();
    size_t pbase = (size_t)(b*64+c)*HH*WW;
    for(int t=tid; t<1296; t+=256){
        int Yl = t/18;
        int Xb = (t%18)*8;
        int yyl = Yl/3, r = Yl%3;
        float vo[8];
        #pragma unroll
        for(int k=0;k<8;++k){
            int X = Xb+k;
            int xx = X/3, sph = X%3;
            int j = 3*r + sph;
            float raw = us2f(sT[j*1152 + yyl*48 + xx]);
            float v = raw*scs[j] + shs[j];
            vo[k] = 1.f/(1.f + __expf(-v));
        }
        size_t off = pbase + (size_t)(yy0*3 + Yl)*WW + Xb;
        if(isf){
            const float4* xp = (const float4*)((const float*)x + off);
            float4 x0 = xp[0], x1 = xp[1];
            float4 o0, o1;
            o0.x = x0.x*vo[0]; o0.y = x0.y*vo[1]; o0.z = x0.z*vo[2]; o0.w = x0.w*vo[3];
            o1.x = x1.x*vo[4]; o1.y = x1.y*vo[5]; o1.z = x1.z*vo[6]; o1.w = x1.w*vo[7];
            float4* op = (float4*)((float*)out + off);
            op[0] = o0; op[1] = o1;
        } else {
            uint4 xr = *(const uint4*)((const us*)x + off);
            const us* xu = (const us*)&xr;
            union { us u[8]; uint4 v; } pk;
            #pragma unroll
            for(int k=0;k<8;++k)
                pk.u[k] = bfbits(us2f(xu[k])*vo[k]);
            *(uint4*)((us*)out + off) = pk.v;
        }
    }
}

// ===========================================================================

extern "C" void kernel_launch(void* const* d_in, const int* in_sizes, int n_in,
                              void* d_out, int out_size, void* d_ws, size_t ws_size,
                              hipStream_t stream) {
    (void)n_in; (void)out_size; (void)ws_size;
    const void* x    = d_in[0];
    const void* wmix = d_in[1];
    const void* gm   = d_in[2];
    const void* bm   = d_in[3];
    const void* wh1  = d_in[4];
    const void* wv1  = d_in[5];
    const void* wh2  = d_in[6];
    const void* wv2  = d_in[7];
    const void* gn   = d_in[8];
    const void* bnb  = d_in[9];

    us* pf = (us*)d_out;          // focus-layout pool in d_out (dead before final)
    char* ws = (char*)d_ws;
    us*    mixed = (us*)   (ws + 0);           // 42467328 B
    us*    att   = (us*)   (ws + 42467328);    //  4718592 B
    float* st1a  = (float*)(ws + 47185920);    // raw sum1 (576)
    float* st1b  = (float*)(ws + 47188224);    // raw ss1  (576)
    float* st2a  = (float*)(ws + 47190528);    // raw sum2 (64)
    float* st2b  = (float*)(ws + 47190784);    // raw ss2  (64)
    int*   flag  = (int*)  (ws + 47191040);

    // Resolve dtype host-side from byte size; fall back to device sniff if
    // in_sizes isn't in bytes (unknown value).
    int isf;
    if(in_sizes[0] == (int)((long long)NTOT*4)) isf = 1;
    else if(in_sizes[0] == (int)((long long)NTOT*2)) isf = 0;
    else isf = -1;

    if(isf < 0)
        k_sniff<<<1, 256, 0, stream>>>((const unsigned int*)x, flag);

#define LAUNCH_ALL(T)                                                          \
    k_pool3<T><<<BB*CC*9, 256, 0, stream>>>(x, pf, flag, st1a);                \
    k_mix3<T><<<BB*9*8, 256, 0, stream>>>(pf, wmix, mixed, st1a, st1b, flag);  \
    k_conv3<T><<<BB*64, 256, 0, stream>>>(mixed, st1a, st1b, gm, bm,           \
                                          wh1, wv1, wh2, wv2, att,             \
                                          st2a, st2b, flag);                   \
    k_final3<T><<<BB*CC*2, 256, 0, stream>>>(x, mixed, att, gm, bm, gn, bnb,   \
                                             st1a, st1b, st2a, st2b, d_out, flag);

    if(isf == 1)      { LAUNCH_ALL(1)  }
    else if(isf == 0) { LAUNCH_ALL(0)  }
    else              { LAUNCH_ALL(-1) }
#undef LAUNCH_ALL
}

// Round 4
// 246.447 us; speedup vs baseline: 1.1728x; 1.0181x over previous
//
#include <hip/hip_runtime.h>
#include <hip/hip_bf16.h>

typedef __hip_bfloat16 bf16;
typedef unsigned short us;
typedef __attribute__((ext_vector_type(8))) short short8;
typedef __attribute__((ext_vector_type(4))) float floatx4;

__device__ __forceinline__ float b2f(bf16 v){ return __bfloat162float(v); }
__device__ __forceinline__ bf16  f2b(float v){ return __float2bfloat16(v); }
__device__ __forceinline__ float ldx(const void* p, size_t i, int isf){
    return isf ? ((const float*)p)[i] : b2f(((const bf16*)p)[i]);
}
__device__ __forceinline__ us bfbits(float v){
    bf16 h = f2b(v); return *(us*)&h;
}
__device__ __forceinline__ float us2f(us u){
    unsigned int w = ((unsigned int)u)<<16; float f; __builtin_memcpy(&f,&w,4); return f;
}
__device__ __forceinline__ float uniformf(float v){
    return __int_as_float(__builtin_amdgcn_readfirstlane(__float_as_int(v)));
}

#define BB   16
#define CC   64
#define HH   144
#define WW   144
#define HS   48
#define SP   (HS*HS)            // 2304
#define NTOT (BB*CC*HH*WW)      // 21233664
#define NCH  36864              // B*SP
#define INV_NCH (1.f/36864.f)

// TISF: 1 = f32, 0 = bf16, -1 = resolve from device flag (sniffer fallback)
template<int TISF>
__device__ __forceinline__ int isf_of(const int* flag){
    if(TISF >= 0) return TISF;
    return *flag;
}

// -------- 0. dtype sniffer (fallback only) ---------------------------------
__global__ void k_sniff(const unsigned int* __restrict__ x, int* __restrict__ flag){
    __shared__ int hit;
    if(threadIdx.x==0) hit = 0;
    __syncthreads();
    int local = 0;
    for(int t=threadIdx.x; t<4096; t+=256){
        unsigned int w = x[t];
        if(((w>>7)&0xFFu)==0xFFu || ((w>>23)&0xFFu)==0xFFu) local = 1;
    }
    if(local) atomicOr(&hit, 1);
    __syncthreads();
    if(threadIdx.x==0) *flag = hit;
}

// -------- 1. maxpool 3x3 s1 p1, writes FOCUS layout (+ stats zeroing) ------
// pf[b][gi][gj][c][y][xx] = maxpool(x)[b,c,3y+gi,3xx+gj]
template<int TISF>
__global__ __launch_bounds__(256) void k_pool3(const void* __restrict__ x,
                                               us* __restrict__ pf,
                                               const int* __restrict__ flag,
                                               float* __restrict__ stats){
    __shared__ float l [18*148];
    __shared__ float hm[18*148];
    int isf = isf_of<TISF>(flag);
    int bid = blockIdx.x;
    int tid = threadIdx.x;
    if(bid==0){                        // zero BN stat accumulators (pre-mix3)
        for(int i=tid; i<1280; i+=256) stats[i] = 0.f;
    }
    int strip = bid % 9;
    int bc = bid / 9;
    int b = bc>>6, c = bc&63;
    int r0 = strip*16;
    size_t base = (size_t)bc*HH*WW;
    // load rows r0-1 .. r0+16 (18 rows x 144), 8-wide vectors
    for(int t=tid; t<18*18; t+=256){
        int row = t/18, ch = t%18;
        int rr = r0-1+row; int c0 = ch*8;
        float v[8];
        if(rr>=0 && rr<HH){
            if(isf){
                const float* xp = (const float*)x + base + (size_t)rr*WW + c0;
                float4 f0 = *(const float4*)xp;
                float4 f1 = *(const float4*)(xp+4);
                v[0]=f0.x;v[1]=f0.y;v[2]=f0.z;v[3]=f0.w;
                v[4]=f1.x;v[5]=f1.y;v[6]=f1.z;v[7]=f1.w;
            } else {
                const us* xp = (const us*)x + base + (size_t)rr*WW + c0;
                uint4 d = *(const uint4*)xp;
                const us* u = (const us*)&d;
                #pragma unroll
                for(int e=0;e<8;++e) v[e] = us2f(u[e]);
            }
        } else {
            #pragma unroll
            for(int e=0;e<8;++e) v[e] = -INFINITY;
        }
        #pragma unroll
        for(int e=0;e<8;++e) l[row*148 + c0 + e] = v[e];
    }
    __syncthreads();
    for(int t=tid; t<18*144; t+=256){
        int row = t/144, cc = t%144;
        float a = l[row*148+cc];
        float bb = (cc>0)   ? l[row*148+cc-1] : -INFINITY;
        float cv = (cc<143) ? l[row*148+cc+1] : -INFINITY;
        hm[row*148+cc] = fmaxf(a, fmaxf(bb,cv));
    }
    __syncthreads();
    // vmax + scatter to focus layout; 4 outputs (same gj) per iter
    for(int t=tid; t<576; t+=256){
        int row = t/36;
        int gj  = (t/12)%3;
        int xg  = t%12;
        int R = r0+row;
        int gi = R%3, y = R/3;
        union { us u[4]; uint2 v; } pk;
        #pragma unroll
        for(int e=0;e<4;++e){
            int xx = xg*4+e; int C = 3*xx+gj;
            float m = fmaxf(hm[row*148+C],
                      fmaxf(hm[(row+1)*148+C], hm[(row+2)*148+C]));
            pk.u[e] = bfbits(m);
        }
        size_t o = ((((size_t)(b*3+gi)*3+gj)*64 + c)*48 + y)*48 + xg*4;
        *(uint2*)&pf[o] = pk.v;
    }
}

// -------- 2. MFMA mixer + BN1 stats ----------------------------------------
// block = (b,g,chunk): C[64 o][288 sites] = W_g[64x64] x I[64x288]
// LDS swizzle: element (row, i) at row*64 + ((i/8 + row)%8)*8 + i%8
// Epilogue: per-wave 16x40-us LDS transpose -> coalesced dwordx4 stores.
template<int TISF>
__global__ __launch_bounds__(256) void k_mix3(const us* __restrict__ pf,
        const void* __restrict__ wmix, us* __restrict__ mixed,
        float* __restrict__ sum1, float* __restrict__ ss1,
        const int* __restrict__ flag){
    __shared__ __align__(16) us sAll[4096 + 288*64];   // sW | sI (sW reused as scratch)
    __shared__ float sS[64], sQ[64];
    us* sW = sAll;
    us* sI = sAll + 4096;
    int isf = isf_of<TISF>(flag);
    int bid = blockIdx.x;
    int chunk = bid%8, g = (bid/8)%9, b = bid/72;
    int gi = g/3, gj = g%3;
    int tid = threadIdx.x, lane = tid&63, w = tid>>6;
    // stage W (swizzled), vectorized global loads: thread -> o=tid/4, i-range 16
    {
        int o  = tid>>2;
        int i0 = (tid&3)*16;
        us wb[16];
        if(isf){
            const float* wp = (const float*)wmix + (size_t)g*4096 + (size_t)o*64 + i0;
            #pragma unroll
            for(int e=0;e<16;e+=4){
                float4 f = *(const float4*)(wp+e);
                wb[e]=bfbits(f.x); wb[e+1]=bfbits(f.y);
                wb[e+2]=bfbits(f.z); wb[e+3]=bfbits(f.w);
            }
        } else {
            const us* wp = (const us*)wmix + (size_t)g*4096 + (size_t)o*64 + i0;
            uint4 d0 = *(const uint4*)wp, d1 = *(const uint4*)(wp+8);
            const us* u0 = (const us*)&d0; const us* u1 = (const us*)&d1;
            #pragma unroll
            for(int e=0;e<8;++e){ wb[e]=u0[e]; wb[8+e]=u1[e]; }
        }
        #pragma unroll
        for(int e=0;e<16;++e){
            int i = i0+e;
            sW[o*64 + ((((i>>3)+o)&7)<<3) + (i&7)] = wb[e];
        }
    }
    if(tid<64){ sS[tid]=0.f; sQ[tid]=0.f; }
    // stage I (swizzled): lane = channel i, wave covers 9 vec8 chunks
    {
        int i = lane;
        const us* src = pf + ((((size_t)(b*3+gi)*3+gj)*64 + i)*48 + (size_t)chunk*6)*48;
        for(int vv=w*9; vv<(w+1)*9; ++vv){
            uint4 d = *(const uint4*)(src + vv*8);
            const us* u = (const us*)&d;
            #pragma unroll
            for(int e=0;e<8;++e){
                int s = vv*8+e;
                sI[s*64 + ((((i>>3)+s)&7)<<3) + (i&7)] = u[e];
            }
        }
    }
    __syncthreads();
    int n = lane&15, quad = lane>>4;
    int m = w*16 + n;   // this wave's A rows (o)
    // A fragments for k0=0 (q2=quad) and k0=32 (q2=4+quad)
    short8 a0 = *(const short8*)&sW[m*64 + (((quad     + m)&7)<<3)];
    short8 a1 = *(const short8*)&sW[m*64 + ((((4+quad) + m)&7)<<3)];
    floatx4 acc[18];
    #pragma unroll
    for(int nt=0; nt<18; ++nt) acc[nt] = (floatx4){0.f,0.f,0.f,0.f};
    #pragma unroll
    for(int nt=0; nt<18; ++nt){
        int site = nt*16 + n;
        short8 b0 = *(const short8*)&sI[site*64 + (((quad     + site)&7)<<3)];
        short8 b1 = *(const short8*)&sI[site*64 + ((((4+quad) + site)&7)<<3)];
        acc[nt] = __builtin_amdgcn_mfma_f32_16x16x32_bf16(a0, b0, acc[nt], 0,0,0);
        acc[nt] = __builtin_amdgcn_mfma_f32_16x16x32_bf16(a1, b1, acc[nt], 0,0,0);
    }
    // per-lane stats.  C layout: col=lane&15 (site), row=quad*4+r (o)
    float s[4] = {0,0,0,0}, q[4] = {0,0,0,0};
    #pragma unroll
    for(int nt=0; nt<18; ++nt){
        #pragma unroll
        for(int r=0;r<4;++r){
            float v = acc[nt][r];
            s[r] += v; q[r] += v*v;
        }
    }
    #pragma unroll
    for(int off=1; off<=8; off<<=1){
        #pragma unroll
        for(int r=0;r<4;++r){
            s[r] += __shfl_xor(s[r], off, 64);
            q[r] += __shfl_xor(q[r], off, 64);
        }
    }
    if(n==0){
        #pragma unroll
        for(int r=0;r<4;++r){
            atomicAdd(&sS[w*16+quad*4+r], s[r]);
            atomicAdd(&sQ[w*16+quad*4+r], q[r]);
        }
    }
    __syncthreads();   // also guarantees all waves done with sW/sI reads
    if(tid<64){
        atomicAdd(&sum1[g*64+tid], sS[tid]);
        atomicAdd(&ss1 [g*64+tid], sQ[tid]);
    }
    // ---- transpose epilogue: per-wave 16x40-us scratch in sW region -------
    // acc[nt][r] = C[o = w*16+quad*4+r][site = nt*16+n]
    us* swr = sAll + w*640;           // 16 rows x 40 us per wave (1280 B)
    int o_loc = lane>>2, s8 = (lane&3)*8;
    size_t rowbase = ((size_t)(b*576 + g*64 + w*16))*SP + (size_t)chunk*288;
    #pragma unroll
    for(int mp=0; mp<9; ++mp){
        __builtin_amdgcn_wave_barrier();
        #pragma unroll
        for(int half=0; half<2; ++half){
            int nt = mp*2 + half;
            #pragma unroll
            for(int r=0;r<4;++r)
                swr[(quad*4+r)*40 + half*16 + n] = bfbits(acc[nt][r]);
        }
        __builtin_amdgcn_wave_barrier();
        uint4 vv = *(const uint4*)&swr[o_loc*40 + s8];
        *(uint4*)&mixed[rowbase + (size_t)o_loc*SP + (size_t)(mp*32 + s8)] = vv;
    }
}

// -------- 3. fused 4-way depthwise conv + BN1 inline + BN2 stats -----------
// 3x3 output register block per thread (2304 = 256 threads x 9 exactly).
// Shared row-windows per thread cut tile LDS reads 105 -> ~25 per output.
// conv3/conv4 weights merged into one 13x3 table w34 (zero-padded at |r|=6);
// out-of-window taps land in zero-padded tile columns with zero weights.
// w1/w2 weights are block-uniform -> SGPRs via readfirstlane (VGPR relief).
template<int TISF>
__global__ __launch_bounds__(256) void k_conv3(const us* __restrict__ mixed,
    const float* __restrict__ sum1, const float* __restrict__ ss1,
    const void* __restrict__ gm, const void* __restrict__ bm,
    const void* __restrict__ wh1, const void* __restrict__ wv1,
    const void* __restrict__ wh2, const void* __restrict__ wv2,
    us* __restrict__ att, float* __restrict__ sum2, float* __restrict__ ss2,
    const int* __restrict__ flag){
    __shared__ float tile[60*60+64];
    __shared__ float w1[33], w2[33], w34[39];
    __shared__ float r1[256], r2[256];
    int isf = isf_of<TISF>(flag);
    int bid = blockIdx.x;
    int b = bid/64, c = bid%64;
    int tid = threadIdx.x;
    for(int t=tid; t<3664; t+=256) tile[t] = 0.f;
    if(tid < 33){
        w1[tid] = ldx(wh1, c*33 + tid, isf);
    } else if(tid < 66){
        w2[tid-33] = ldx(wv1, c*33 + (tid-33), isf);
    } else if(tid < 105){
        int k = tid-66;            // 0..38 : 13 rows x 3
        int r = k/3 - 6;           // row offset -6..6
        int vo = k%3 - 1;          // original v  -1..1
        float a = 0.f;
        if(r >= -5 && r <= 5)      // conv3 (h-transform), u = r
            a += ldx(wh2, c*33 + (r+5)*3 + (vo+1), isf);
        int u = vo - r;            // conv4 (v-transform), row off = vo-u
        if(u >= -5 && u <= 5)
            a += ldx(wv2, c*33 + (vo+1)*11 + (u+5), isf);
        w34[k] = a;
    }
    __syncthreads();
    // BN1 params for this channel (computed from raw sums)
    float mu   = sum1[c]*INV_NCH;
    float var  = ss1[c]*INV_NCH - mu*mu;
    float is   = rsqrtf(var + 1e-5f)*ldx(gm,c,isf);
    float be   = ldx(bm,c,isf);
    const us* src = mixed + (size_t)(b*576 + c)*SP;
    // weights -> registers.  w1/w2 block-uniform -> SGPR; w34 -> VGPR.
    float w1r[33], w2r[33], w34r[39];
    #pragma unroll
    for(int i=0;i<33;++i) w1r[i] = uniformf(w1[i]);
    #pragma unroll
    for(int i=0;i<33;++i) w2r[i] = uniformf(w2[i]);
    #pragma unroll
    for(int i=0;i<39;++i) w34r[i] = w34[i];
    for(int t=tid; t<288; t+=256){
        int h = t/6, w0 = (t%6)*8;
        uint4 d = *(const uint4*)(src + t*8);
        const us* u = (const us*)&d;
        #pragma unroll
        for(int e=0;e<8;++e)
            tile[(h+6)*60 + (w0+6) + e] = (us2f(u[e]) - mu)*is + be;
    }
    __syncthreads();
    // thread -> 3x3 output tile: cols W0..W0+2, rows H0..H0+2
    const int cg = tid & 15, rg = tid >> 4;
    const int W0 = cg*3, H0 = rg*3;
    const float* tb = &tile[(H0+6)*60 + (W0+6)];
    float acc[3][3] = {{0.f,0.f,0.f},{0.f,0.f,0.f},{0.f,0.f,0.f}};
    // conv2 (3x11): 5 shared rows of 13
    #pragma unroll
    for(int ry=-1; ry<=3; ++ry){
        float R[13];
        #pragma unroll
        for(int k=0;k<13;++k) R[k] = tb[ry*60 + (k-5)];
        #pragma unroll
        for(int dy=0; dy<3; ++dy){
            if(ry-dy < -1 || ry-dy > 1) continue;
            #pragma unroll
            for(int dc=0; dc<3; ++dc)
                #pragma unroll
                for(int v=-5; v<=5; ++v)
                    acc[dy][dc] += w2r[(ry-dy+1)*11 + (v+5)] * R[dc+v+5];
        }
    }
    // conv1 (11x3): 13 shared rows of 5
    #pragma unroll
    for(int ry=-5; ry<=7; ++ry){
        float R[5];
        #pragma unroll
        for(int k=0;k<5;++k) R[k] = tb[ry*60 + (k-1)];
        #pragma unroll
        for(int dy=0; dy<3; ++dy){
            if(ry-dy < -5 || ry-dy > 5) continue;
            #pragma unroll
            for(int dc=0; dc<3; ++dc)
                #pragma unroll
                for(int v=-1; v<=1; ++v)
                    acc[dy][dc] += w1r[(ry-dy+5)*3 + (v+1)] * R[dc+v+1];
        }
    }
    // merged conv3+conv4 (13x3 diagonal): 15 shared rows of <=7
    #pragma unroll
    for(int ry=-6; ry<=8; ++ry){
        const int dyLo = (ry-6 > 0) ? ry-6 : 0;
        const int dyHi = (ry+6 < 2) ? ry+6 : 2;
        const int jLo  = (dyLo - ry) - 1;      // j = (dy-ry)+dc+v
        float R[7];
        #pragma unroll
        for(int k=0;k<7;++k) R[k] = tb[ry*60 + jLo + k];
        #pragma unroll
        for(int dy=0; dy<3; ++dy){
            if(dy < dyLo || dy > dyHi) continue;
            #pragma unroll
            for(int dc=0; dc<3; ++dc)
                #pragma unroll
                for(int v=-1; v<=1; ++v)
                    acc[dy][dc] += w34r[(ry-dy+6)*3 + (v+1)] * R[(dy-ry)+dc+v - jLo];
        }
    }
    // store + BN2 stats
    us* out = att + (size_t)(b*64 + c)*SP;
    float sl = 0.f, ql = 0.f;
    #pragma unroll
    for(int dy=0; dy<3; ++dy)
        #pragma unroll
        for(int dc=0; dc<3; ++dc){
            float a = acc[dy][dc];
            out[(H0+dy)*48 + W0+dc] = bfbits(a);
            sl += a; ql += a*a;
        }
    r1[tid]=sl; r2[tid]=ql; __syncthreads();
    for(int o=128;o>0;o>>=1){
        if(tid<o){ r1[tid]+=r1[tid+o]; r2[tid]+=r2[tid+o]; }
        __syncthreads();
    }
    if(tid==0){
        atomicAdd(&sum2[c], r1[0]);
        atomicAdd(&ss2 [c], r2[0]);
    }
}

// -------- 4. final: BN + pixel_shuffle + sigmoid gate (y-split) ------------
template<int TISF>
__global__ __launch_bounds__(256) void k_final3(const void* __restrict__ x,
    const us* __restrict__ mixed, const us* __restrict__ att,
    const void* __restrict__ gm, const void* __restrict__ bm,
    const void* __restrict__ gn, const void* __restrict__ bnb,
    const float* __restrict__ sum1, const float* __restrict__ ss1,
    const float* __restrict__ sum2, const float* __restrict__ ss2,
    void* __restrict__ out, const int* __restrict__ flag){
    __shared__ __align__(16) us sT[9*1152];
    __shared__ float scs[9], shs[9];
    int isf = isf_of<TISF>(flag);
    int bid = blockIdx.x;
    int half = bid&1, c = (bid>>1)&63, b = bid>>7;
    int yy0 = half*24;
    int tid = threadIdx.x;
    if(tid < 9){
        int f = 9*c + tid;
        float sraw, qraw, gg, bb2;
        if(f < 64){ sraw = sum2[f]; qraw = ss2[f]; gg = ldx(gn,f,isf);  bb2 = ldx(bnb,f,isf); }
        else      { sraw = sum1[f]; qraw = ss1[f]; gg = ldx(gm,f,isf);  bb2 = ldx(bm,f,isf); }
        float mm  = sraw*INV_NCH;
        float ist = rsqrtf(qraw*INV_NCH - mm*mm + 1e-5f);
        float sc = ist*gg;
        scs[tid] = sc;
        shs[tid] = bb2 - mm*sc;
    }
    for(int t=tid; t<9*144; t+=256){
        int j = t/144, qq = t%144;
        int f = 9*c + j;
        const us* srcp = ((f<64) ? att   + (size_t)(b*64 +f)*SP
                                 : mixed + (size_t)(b*576+f)*SP) + yy0*48;
        ((uint4*)&sT[j*1152])[qq] = ((const uint4*)srcp)[qq];
    }
    __syncthreads();
    size_t pbase = (size_t)(b*64+c)*HH*WW;
    for(int t=tid; t<1296; t+=256){
        int Yl = t/18;
        int Xb = (t%18)*8;
        int yyl = Yl/3, r = Yl%3;
        float vo[8];
        #pragma unroll
        for(int k=0;k<8;++k){
            int X = Xb+k;
            int xx = X/3, sph = X%3;
            int j = 3*r + sph;
            float raw = us2f(sT[j*1152 + yyl*48 + xx]);
            float v = raw*scs[j] + shs[j];
            vo[k] = 1.f/(1.f + __expf(-v));
        }
        size_t off = pbase + (size_t)(yy0*3 + Yl)*WW + Xb;
        if(isf){
            const float4* xp = (const float4*)((const float*)x + off);
            float4 x0 = xp[0], x1 = xp[1];
            float4 o0, o1;
            o0.x = x0.x*vo[0]; o0.y = x0.y*vo[1]; o0.z = x0.z*vo[2]; o0.w = x0.w*vo[3];
            o1.x = x1.x*vo[4]; o1.y = x1.y*vo[5]; o1.z = x1.z*vo[6]; o1.w = x1.w*vo[7];
            float4* op = (float4*)((float*)out + off);
            op[0] = o0; op[1] = o1;
        } else {
            uint4 xr = *(const uint4*)((const us*)x + off);
            const us* xu = (const us*)&xr;
            union { us u[8]; uint4 v; } pk;
            #pragma unroll
            for(int k=0;k<8;++k)
                pk.u[k] = bfbits(us2f(xu[k])*vo[k]);
            *(uint4*)((us*)out + off) = pk.v;
        }
    }
}

// ===========================================================================

extern "C" void kernel_launch(void* const* d_in, const int* in_sizes, int n_in,
                              void* d_out, int out_size, void* d_ws, size_t ws_size,
                              hipStream_t stream) {
    (void)n_in; (void)out_size; (void)ws_size;
    const void* x    = d_in[0];
    const void* wmix = d_in[1];
    const void* gm   = d_in[2];
    const void* bm   = d_in[3];
    const void* wh1  = d_in[4];
    const void* wv1  = d_in[5];
    const void* wh2  = d_in[6];
    const void* wv2  = d_in[7];
    const void* gn   = d_in[8];
    const void* bnb  = d_in[9];

    us* pf = (us*)d_out;          // focus-layout pool in d_out (dead before final)
    char* ws = (char*)d_ws;
    us*    mixed = (us*)   (ws + 0);           // 42467328 B
    us*    att   = (us*)   (ws + 42467328);    //  4718592 B
    float* st1a  = (float*)(ws + 47185920);    // raw sum1 (576)
    float* st1b  = (float*)(ws + 47188224);    // raw ss1  (576)
    float* st2a  = (float*)(ws + 47190528);    // raw sum2 (64)
    float* st2b  = (float*)(ws + 47190784);    // raw ss2  (64)
    int*   flag  = (int*)  (ws + 47191040);

    // Resolve dtype host-side from byte size; fall back to device sniff if
    // in_sizes isn't in bytes (unknown value).
    int isf;
    if(in_sizes[0] == (int)((long long)NTOT*4)) isf = 1;
    else if(in_sizes[0] == (int)((long long)NTOT*2)) isf = 0;
    else isf = -1;

    if(isf < 0)
        k_sniff<<<1, 256, 0, stream>>>((const unsigned int*)x, flag);

#define LAUNCH_ALL(T)                                                          \
    k_pool3<T><<<BB*CC*9, 256, 0, stream>>>(x, pf, flag, st1a);                \
    k_mix3<T><<<BB*9*8, 256, 0, stream>>>(pf, wmix, mixed, st1a, st1b, flag);  \
    k_conv3<T><<<BB*64, 256, 0, stream>>>(mixed, st1a, st1b, gm, bm,           \
                                          wh1, wv1, wh2, wv2, att,             \
                                          st2a, st2b, flag);                   \
    k_final3<T><<<BB*CC*2, 256, 0, stream>>>(x, mixed, att, gm, bm, gn, bnb,   \
                                             st1a, st1b, st2a, st2b, d_out, flag);

    if(isf == 1)      { LAUNCH_ALL(1)  }
    else if(isf == 0) { LAUNCH_ALL(0)  }
    else              { LAUNCH_ALL(-1) }
#undef LAUNCH_ALL
}